// Round 8
// baseline (32.308 us; speedup 1.0000x reference)
//
#include <hip/hip_runtime.h>

#define TWO_PI 6.2831853071795864769f

// ws layout (bytes):
//   x1   f32[12*6*256] @ 0       (73728)   stage-0 output
//   x2   f32[12*6*256] @ 73728   (73728)   stage-1 output
//   cnt  int[16]       @ 147456
//   wde  int[6][2048]  @ 147520  (49152)   winner (d<<8)|e per b
//   wv1  f32[6][2048]  @ 196672  (49152)   stage-1 corrections (T11 - P1)
//   wv2  f32[6][2048]  @ 245824  (49152)   stage-2 corrections (T14 - P1)

// Stage kernels: grid = 6 b x 4 e-tiles(64) = 24 blocks x 512 threads.
// thread = (dg 0..15, e2 0..31): computes att[all 12 h, b, e-tile] with the
// (P1 + 0.975*P3) tile streamed ONCE per stage per tile (fused inline, no C
// buffer) feeding 12 h-FMAs per element -> kills the 12x redundant per-CU
// streaming of rounds 3-7 (72 blocks each privately pulling 256-512 KB).

__global__ __launch_bounds__(512) void stage0_kernel(
    const float* __restrict__ P1, const float* __restrict__ P2,
    const float* __restrict__ P3, const float* __restrict__ T4,
    const float* __restrict__ T11, const float* __restrict__ T14,
    const int* __restrict__ p5, const int* __restrict__ p6,
    const int* __restrict__ p7, const int* __restrict__ p8,
    const float* __restrict__ f1, const float* __restrict__ ph1,
    float* __restrict__ x1, int* __restrict__ cnt,
    int* __restrict__ wde_g, float* __restrict__ wv1_g,
    float* __restrict__ wv2_g, int K)
{
    __shared__ float v[12 * 256];        // 12 KB  stage input (P2 slice)
    __shared__ float ps[16 * 12 * 64];   // 48 KB  per-dgroup partials
    __shared__ float om[12 * 64];        // 3 KB   merged output tile
    __shared__ float mf[64];
    __shared__ unsigned pk[2048];        // 8 KB   packed (b,c,d,e)
    __shared__ unsigned hmap[2048];      // 8 KB   per-b winner hash
    __shared__ int nwl;

    const int tid = (int)threadIdx.x;
    const int b  = (int)blockIdx.x >> 2;
    const int t  = (int)blockIdx.x & 3;
    const int e0 = t << 6;
    const int e2 = tid & 31;             // float2 lane: e = e0 + e2*2 .. +1
    const int dg = tid >> 5;             // 0..15, 16 d per group

    // ---- init: pk staging, hash init, v load, modulation ----
    for (int k = tid; k < K; k += 512)
        pk[k] = ((unsigned)p5[k] << 24) | ((unsigned)p6[k] << 16) |
                ((unsigned)p7[k] << 8) | (unsigned)p8[k];
    for (int i = tid; i < 2048; i += 512) hmap[i] = 0xFFFFFFFFu;
    for (int i = tid; i < 3072; i += 512)
        v[i] = P2[(((i >> 8) * 6 + b) << 8) | (i & 255)];
    if (tid < 64) {
        float arg = (float)(e0 + tid) * TWO_PI * f1[0] + ph1[0];
        float sn = __sinf(arg);
        mf[tid] = 1.0f / (sn * sn * 0.1f + 0.95f);   // stage0: divide
    }
    if (tid == 0) nwl = 0;
    __syncthreads();

    // ---- hash insert (its-b only): last-write-wins = max k per (d,e) ----
    for (int k = tid; k < K; k += 512) {
        unsigned pv = pk[k];
        if ((pv >> 24) != (unsigned)b) continue;
        unsigned key = pv & 0xFFFFu;                 // (d<<8)|e
        unsigned mine = (key << 12) | (unsigned)k;   // k < 4096
        unsigned hh = (key * 2654435761u) >> 21;     // [0,2048)
        for (;;) {
            unsigned prev = atomicCAS(&hmap[hh], 0xFFFFFFFFu, mine);
            if (prev == 0xFFFFFFFFu) break;
            if ((prev >> 12) == key) { atomicMax(&hmap[hh], mine); break; }
            hh = (hh + 1) & 2047u;
        }
    }

    // ---- dense: stream (P1+0.975*P3) tile once, 12 h accumulators ----
    const float2* P1v = (const float2*)P1 + (b << 15) + (dg << 11) + (e0 >> 1) + e2;
    const float2* P3v = (const float2*)P3 + (b << 15) + (dg << 11) + (e0 >> 1) + e2;
    float2 acc[12];
    #pragma unroll
    for (int h = 0; h < 12; ++h) acc[h] = make_float2(0.f, 0.f);
    #pragma unroll
    for (int dd = 0; dd < 16; ++dd) {
        float2 a = P1v[dd << 7];
        float2 p = P3v[dd << 7];
        float cx = fmaf(p.x, 0.975f, a.x);
        float cy = fmaf(p.y, 0.975f, a.y);
        const int d = (dg << 4) + dd;
        #pragma unroll
        for (int h = 0; h < 12; ++h) {
            float vv = v[(h << 8) | d];              // 2-way LDS broadcast
            acc[h].x = fmaf(vv, cx, acc[h].x);
            acc[h].y = fmaf(vv, cy, acc[h].y);
        }
    }
    #pragma unroll
    for (int h = 0; h < 12; ++h)
        *(float2*)&ps[((dg * 12 + h) << 6) + (e2 << 1)] = acc[h];
    __syncthreads();

    // ---- merge 16 -> 1 ----
    for (int idx = tid; idx < 768; idx += 512) {
        int h = idx >> 6, e = idx & 63;
        float s = 0.f;
        #pragma unroll
        for (int g = 0; g < 16; ++g) s += ps[((g * 12 + h) << 6) | e];
        om[idx] = s;
    }
    __syncthreads();

    // ---- winner readback: apply in-tile corrections; tile0 exports lists ----
    for (int k = tid; k < K; k += 512) {
        unsigned pv = pk[k];
        if ((pv >> 24) != (unsigned)b) continue;
        unsigned key = pv & 0xFFFFu;
        unsigned hh = (key * 2654435761u) >> 21;
        unsigned cur;
        for (;;) {
            cur = hmap[hh];
            if ((cur >> 12) == key) break;
            hh = (hh + 1) & 2047u;
        }
        if ((cur & 0xFFFu) == (unsigned)k) {         // last write wins
            int c = (int)((pv >> 16) & 0xFFu);
            int d_w = (int)(key >> 8), e_w = (int)(key & 255u);
            float p1v = P1[(b << 16) | (int)key];
            if ((unsigned)(e_w - e0) < 64u) {
                float val0 = T4[(b << 8) | c] - p1v;
                #pragma unroll
                for (int h = 0; h < 12; ++h)
                    atomicAdd(&om[(h << 6) | (e_w - e0)],
                              v[(h << 8) | d_w] * val0);
            }
            if (t == 0) {
                int w = atomicAdd(&nwl, 1);
                wde_g[(b << 11) + w] = (int)key;
                wv1_g[(b << 11) + w] = T11[(b << 8) | c] - p1v;
                wv2_g[(b << 11) + w] = T14[(b << 8) | c] - p1v;
            }
        }
    }
    __syncthreads();

    // ---- modulate + store ----
    for (int idx = tid; idx < 768; idx += 512) {
        int h = idx >> 6, e = idx & 63;
        x1[(((h * 6 + b)) << 8) | (e0 + e)] = om[idx] * mf[e];
    }
    if (t == 0 && tid == 0) cnt[b] = nwl;
}

__global__ __launch_bounds__(512) void stage12_kernel(
    const float* __restrict__ P1, const float* __restrict__ P3,
    const float* __restrict__ VIN, float* __restrict__ VOUT,
    const int* __restrict__ cnt, const int* __restrict__ wde_g,
    const float* __restrict__ wv_g,
    const float* __restrict__ fr, const float* __restrict__ ph,
    int mulflag)
{
    __shared__ float v[12 * 256];
    __shared__ float ps[16 * 12 * 64];
    __shared__ float om[12 * 64];
    __shared__ float mf[64];

    const int tid = (int)threadIdx.x;
    const int b  = (int)blockIdx.x >> 2;
    const int t  = (int)blockIdx.x & 3;
    const int e0 = t << 6;
    const int e2 = tid & 31;
    const int dg = tid >> 5;

    for (int i = tid; i < 3072; i += 512)
        v[i] = VIN[(((i >> 8) * 6 + b) << 8) | (i & 255)];
    if (tid < 64) {
        float arg = (float)(e0 + tid) * TWO_PI * fr[0] + ph[0];
        float sn = __sinf(arg);
        float mm = sn * sn * 0.1f + 0.95f;
        mf[tid] = mulflag ? mm : 1.0f / mm;
    }
    __syncthreads();

    const float2* P1v = (const float2*)P1 + (b << 15) + (dg << 11) + (e0 >> 1) + e2;
    const float2* P3v = (const float2*)P3 + (b << 15) + (dg << 11) + (e0 >> 1) + e2;
    float2 acc[12];
    #pragma unroll
    for (int h = 0; h < 12; ++h) acc[h] = make_float2(0.f, 0.f);
    #pragma unroll
    for (int dd = 0; dd < 16; ++dd) {
        float2 a = P1v[dd << 7];
        float2 p = P3v[dd << 7];
        float cx = fmaf(p.x, 0.975f, a.x);
        float cy = fmaf(p.y, 0.975f, a.y);
        const int d = (dg << 4) + dd;
        #pragma unroll
        for (int h = 0; h < 12; ++h) {
            float vv = v[(h << 8) | d];
            acc[h].x = fmaf(vv, cx, acc[h].x);
            acc[h].y = fmaf(vv, cy, acc[h].y);
        }
    }
    #pragma unroll
    for (int h = 0; h < 12; ++h)
        *(float2*)&ps[((dg * 12 + h) << 6) + (e2 << 1)] = acc[h];
    __syncthreads();

    for (int idx = tid; idx < 768; idx += 512) {
        int h = idx >> 6, e = idx & 63;
        float s = 0.f;
        #pragma unroll
        for (int g = 0; g < 16; ++g) s += ps[((g * 12 + h) << 6) | e];
        om[idx] = s;
    }
    __syncthreads();

    const int n = cnt[b];
    for (int i = tid; i < n; i += 512) {
        int de = wde_g[(b << 11) + i];
        int e_w = de & 255;
        if ((unsigned)(e_w - e0) >= 64u) continue;
        int d_w = de >> 8;
        float val = wv_g[(b << 11) + i];
        #pragma unroll
        for (int h = 0; h < 12; ++h)
            atomicAdd(&om[(h << 6) | (e_w - e0)], v[(h << 8) | d_w] * val);
    }
    __syncthreads();

    for (int idx = tid; idx < 768; idx += 512) {
        int h = idx >> 6, e = idx & 63;
        VOUT[(((h * 6 + b)) << 8) | (e0 + e)] = om[idx] * mf[e];
    }
}

extern "C" void kernel_launch(void* const* d_in, const int* in_sizes, int n_in,
                              void* d_out, int out_size, void* d_ws, size_t ws_size,
                              hipStream_t stream)
{
    (void)n_in; (void)out_size; (void)ws_size;
    const float* P1  = (const float*)d_in[0];
    const float* P2  = (const float*)d_in[1];
    const float* P3  = (const float*)d_in[2];
    const float* T4  = (const float*)d_in[3];
    const int*   p5  = (const int*)d_in[4];
    const int*   p6  = (const int*)d_in[5];
    const int*   p7  = (const int*)d_in[6];
    const int*   p8  = (const int*)d_in[7];
    const float* f1  = (const float*)d_in[8];
    const float* ph1 = (const float*)d_in[9];
    const float* T11 = (const float*)d_in[10];
    const float* f2  = (const float*)d_in[11];
    const float* ph2 = (const float*)d_in[12];
    const float* T14 = (const float*)d_in[13];
    const float* f3  = (const float*)d_in[14];
    const float* ph3 = (const float*)d_in[15];
    float* out = (float*)d_out;
    int K = in_sizes[4];

    char* ws = (char*)d_ws;
    float* x1    = (float*)(ws);
    float* x2    = (float*)(ws + 73728);
    int*   cnt   = (int*)  (ws + 147456);
    int*   wde_g = (int*)  (ws + 147520);
    float* wv1_g = (float*)(ws + 196672);
    float* wv2_g = (float*)(ws + 245824);

    hipLaunchKernelGGL(stage0_kernel, dim3(24), dim3(512), 0, stream,
                       P1, P2, P3, T4, T11, T14, p5, p6, p7, p8,
                       f1, ph1, x1, cnt, wde_g, wv1_g, wv2_g, K);
    hipLaunchKernelGGL(stage12_kernel, dim3(24), dim3(512), 0, stream,
                       P1, P3, x1, x2, cnt, wde_g, wv1_g, f2, ph2, 1);
    hipLaunchKernelGGL(stage12_kernel, dim3(24), dim3(512), 0, stream,
                       P1, P3, x2, out, cnt, wde_g, wv2_g, f3, ph3, 0);
}